// Round 6
// baseline (218.072 us; speedup 1.0000x reference)
//
#include <hip/hip_runtime.h>
#include <stdint.h>

// Problem constants: B=4, C=256, H=W=64 -> HW=4096, vis=1024
#define B_   4
#define C_   256
#define HW_  4096
#define VIS_ 1024
#define KE_  768      // expanded K: [hi,hi,lo] x [hi,lo,hi] f16 split

using half8   = __attribute__((ext_vector_type(8))) _Float16;
using floatx4 = __attribute__((ext_vector_type(4))) float;

__device__ __forceinline__ unsigned mapf(float v) {
    unsigned u = __float_as_uint(v);
    return (u & 0x80000000u) ? ~u : (u | 0x80000000u);
}

__global__ void init_ws_kernel(unsigned long long* ws, int n) {
    int i = blockIdx.x * blockDim.x + threadIdx.x;
    if (i < n) ws[i] = 0ull;
}

__global__ void finalize_kernel(const unsigned long long* __restrict__ ws,
                                float* __restrict__ out1, int n) {
    int i = blockIdx.x * blockDim.x + threadIdx.x;
    if (i < n) {
        unsigned kinv = (unsigned)(ws[i] & 0xFFFFFFFFull);
        out1[i] = (float)(HW_ - 1 - (int)kinv);
    }
}

// ---------------- f16-split MFMA path ----------------

__global__ __launch_bounds__(256) void split_transpose_kernel(
    const float* __restrict__ Q, const float* __restrict__ K,
    _Float16* __restrict__ Aexp, _Float16* __restrict__ Bexp,
    unsigned long long* __restrict__ keys)
{
    __shared__ float tile[64][65];   // [c][hw], pad 65 to break 8-col bank aliasing
    const int t = threadIdx.x;
    if (blockIdx.y == 0 && blockIdx.z == 0)
        keys[blockIdx.x * 256 + t] = 0ull;   // 64 blocks x 256 thr = 16384 = B_*HW_

    const int hw0 = blockIdx.x * 64;
    const int c0  = blockIdx.y * 64;
    const int z = blockIdx.z, b = z >> 1, which = z & 1;
    const float* src = (which ? K : Q) + (size_t)b * C_ * HW_;
    _Float16* dst = (which ? Bexp : Aexp) + (size_t)b * HW_ * KE_;

    #pragma unroll
    for (int i = 0; i < 4; ++i) {
        int c  = (t >> 4) + i * 16;
        int hw = (t & 15) * 4;
        float4 v = *(const float4*)(src + (size_t)(c0 + c) * HW_ + hw0 + hw);
        tile[c][hw] = v.x; tile[c][hw+1] = v.y; tile[c][hw+2] = v.z; tile[c][hw+3] = v.w;
    }
    __syncthreads();

    #pragma unroll
    for (int i = 0; i < 2; ++i) {
        int id  = t + i * 256;       // 0..511
        int row = id >> 3;           // hw within tile
        int c8  = (id & 7) * 8;      // c offset within 64
        half8 h8, l8;
        #pragma unroll
        for (int j = 0; j < 8; ++j) {
            float v = tile[c8 + j][row];
            _Float16 h = (_Float16)v;
            h8[j] = h;
            l8[j] = (_Float16)(v - (float)h);
        }
        _Float16* base = dst + (size_t)(hw0 + row) * KE_ + c0 + c8;
        *(half8*)(base + 0 * C_) = h8;
        *(half8*)(base + 1 * C_) = which ? l8 : h8;
        *(half8*)(base + 2 * C_) = which ? h8 : l8;
    }
}

__device__ __forceinline__ void gl2lds16(const _Float16* g, _Float16* l) {
    __builtin_amdgcn_global_load_lds(
        (const __attribute__((address_space(1))) void*)g,
        (__attribute__((address_space(3))) void*)l, 16, 0, 0);
}

// ---- 256x256 / BK=32 quad-buffered GEMM with CROSS-PHASE REG PREFETCH ----
//
// Round-6 change: break the ds_read <-> MFMA pipe alternation. Fragments
// for tile T+1 are ISSUED before tile T's MFMA block and WAITED after it
// (LGKM0 at sub-phase end). Register double-buffer: aM0/aM1 ping-pong by
// sub-phase; bA/bB ping-pong by tile parity (static unroll, rule 20).
// Reads balanced 6/6 per sub-phase (576 cyc/CU) < MFMA 16/sub (621 cyc)
// -> MFMA pipe dominant. One VMC(8) per tile.
//
// Per tile T (2 sub-phases, 2 barriers):
//  sub0: ds_read a_mq1(T), b(T+1)[0:2] ; MFMA mq0(T) ; LGKM0 ; BARRIER
//  sub1: stage A/B(T+4) ; ds_read b(T+1)[2:4], a_mq0(T+1) ; MFMA mq1(T) ;
//        LGKM0 ; VMC(8) ; BARRIER
// RAW: tile X reads X+1's LDS; VMC(8)@T forces <=T+2 landed (outstanding
//      12 -> 8: drains oldest 4 = T+2). Prologue VMC(8) forces T0,T1.
// WAR: stage(T+4) overwrites region T&3; all region-T reads (a_mq0@T-1.sub1,
//      b@T-1, a_mq1@T.sub0) are LGKM0'd before the sub0-end barrier.
// Tail (T=20..23): no stages; VMC(4)@20 forces T22, VMC(0)@21 forces T23;
//      T22/23 computed barrier-free (LDS read-only).
//
// Region map: A(db)=lds+(db*2+0)*8192, B(db)=lds+(db*2+1)*8192, db=T&3.
// Chunk swizzle (involution on 16B chunks within a 64B row):
//   lds chunk (row, ch) holds global chunk ch ^ ((row>>1)&3)

#define BARRIER __builtin_amdgcn_s_barrier()
#define LGKM0   asm volatile("s_waitcnt lgkmcnt(0)" ::: "memory")
#define VMC(n)  asm volatile("s_waitcnt vmcnt(" #n ")" ::: "memory")
#define SCHEDB  __builtin_amdgcn_sched_barrier(0)

__device__ __forceinline__ void stage_half(const _Float16* __restrict__ g,
                                           _Float16* lb, int t, int kbase)
{
    #pragma unroll
    for (int j = 0; j < 2; ++j) {
        const int c   = t + j * 512;
        const int row = c >> 2;
        const int ch  = (c & 3) ^ ((row >> 1) & 3);
        gl2lds16(g + (size_t)row * KE_ + kbase + ch * 8, lb + c * 8);
    }
}

template<int MQ>
__device__ __forceinline__ void ds_load_a(const _Float16* base, int wave_m, int s,
                                          int quad, half8 (&a)[4]) {
    #pragma unroll
    for (int mi = 0; mi < 4; ++mi) {
        int row = wave_m * 128 + MQ * 64 + mi * 16 + s;
        int ch  = quad ^ ((row >> 1) & 3);
        a[mi] = *(const half8*)(base + row * 32 + ch * 8);
    }
}

template<int NI0>
__device__ __forceinline__ void ds_load_b2(const _Float16* base, int wave_n, int s,
                                           int quad, half8 (&bfr)[4]) {
    #pragma unroll
    for (int ni = NI0; ni < NI0 + 2; ++ni) {
        int col = wave_n * 64 + ni * 16 + s;
        int ch  = quad ^ ((col >> 1) & 3);
        bfr[ni] = *(const half8*)(base + col * 32 + ch * 8);
    }
}

template<int MQ>
__device__ __forceinline__ void do_mfma(const half8 (&a)[4], const half8 (&bfr)[4],
                                        floatx4 (&acc)[8][4]) {
    __builtin_amdgcn_s_setprio(1);
    #pragma unroll
    for (int mi = 0; mi < 4; ++mi)
        #pragma unroll
        for (int ni = 0; ni < 4; ++ni)
            acc[MQ * 4 + mi][ni] = __builtin_amdgcn_mfma_f32_16x16x32_f16(
                a[mi], bfr[ni], acc[MQ * 4 + mi][ni], 0, 0, 0);
    __builtin_amdgcn_s_setprio(0);
}

__global__ __launch_bounds__(512, 2) void gemm_mfma_kernel(
    const _Float16* __restrict__ Aexp, const _Float16* __restrict__ Bexp,
    float* __restrict__ out0, unsigned long long* __restrict__ keys)
{
    __shared__ __align__(16) _Float16 lds[65536];   // 128 KiB = 8 regions x 16 KB

    const int t      = threadIdx.x;
    const int lane   = t & 63;
    const int wave   = t >> 6;
    const int quad   = lane >> 4;
    const int s      = lane & 15;
    const int wave_m = wave >> 2;     // 0..1 -> 128 output rows
    const int wave_n = wave & 3;      // 0..3 -> 64 output cols

    // T1: XCD-bijective swizzle (kept; harmless).
    const int n    = blockIdx.x;
    const int wgid = (n & 7) * 128 + (n >> 3);
    const int kt   = wgid & 15;
    const int qt   = (wgid >> 4) & 15;
    const int b    = wgid >> 8;

    const _Float16* Agl = Aexp + (size_t)b * HW_ * KE_ + (size_t)(qt * 256) * KE_;
    const _Float16* Bgl = Bexp + (size_t)b * HW_ * KE_ + (size_t)(kt * 256) * KE_;

    // region base helpers (runtime db, static layout)
    #define AR(db) (lds + (db) * 2 * 8192)
    #define BR(db) (lds + ((db) * 2 + 1) * 8192)

    // Prologue: stage tiles 0..3; VMC(8) forces T0,T1 landed; read T0 frags.
    stage_half(Agl, AR(0), t, 0);
    stage_half(Bgl, BR(0), t, 0);
    stage_half(Agl, AR(1), t, 32);
    stage_half(Bgl, BR(1), t, 32);
    stage_half(Agl, AR(2), t, 64);
    stage_half(Bgl, BR(2), t, 64);
    stage_half(Agl, AR(3), t, 96);
    stage_half(Bgl, BR(3), t, 96);
    VMC(8);
    BARRIER; SCHEDB;

    half8 aM0[4], aM1[4], bA[4], bB[4];
    floatx4 acc[8][4] = {};

    ds_load_a<0>(AR(0), wave_m, s, quad, aM0);
    ds_load_b2<0>(BR(0), wave_n, s, quad, bA);
    ds_load_b2<2>(BR(0), wave_n, s, quad, bA);
    LGKM0;
    BARRIER; SCHEDB;

    // Main loop: tiles 0..19 (stage T+4 <= 23), parity-unrolled x2.
    #pragma unroll 1
    for (int j = 0; j < 10; ++j) {
        const int T0  = 2 * j;
        const int db0 = T0 & 3, db1 = (T0 + 1) & 3, db2 = (T0 + 2) & 3;
        // ---- even tile T0: cur b = bA, prefetch -> bB ----
        // sub0
        ds_load_a<1>(AR(db0), wave_m, s, quad, aM1);
        ds_load_b2<0>(BR(db1), wave_n, s, quad, bB);
        do_mfma<0>(aM0, bA, acc);
        LGKM0;
        BARRIER; SCHEDB;
        // sub1
        stage_half(Agl, AR(db0), t, (T0 + 4) * 32);
        stage_half(Bgl, BR(db0), t, (T0 + 4) * 32);
        ds_load_b2<2>(BR(db1), wave_n, s, quad, bB);
        ds_load_a<0>(AR(db1), wave_m, s, quad, aM0);
        do_mfma<1>(aM1, bA, acc);
        LGKM0;
        VMC(8);
        BARRIER; SCHEDB;
        // ---- odd tile T0+1: cur b = bB, prefetch -> bA ----
        // sub0
        ds_load_a<1>(AR(db1), wave_m, s, quad, aM1);
        ds_load_b2<0>(BR(db2), wave_n, s, quad, bA);
        do_mfma<0>(aM0, bB, acc);
        LGKM0;
        BARRIER; SCHEDB;
        // sub1
        stage_half(Agl, AR(db1), t, (T0 + 5) * 32);
        stage_half(Bgl, BR(db1), t, (T0 + 5) * 32);
        ds_load_b2<2>(BR(db2), wave_n, s, quad, bA);
        ds_load_a<0>(AR(db2), wave_m, s, quad, aM0);
        do_mfma<1>(aM1, bB, acc);
        LGKM0;
        VMC(8);
        BARRIER; SCHEDB;
    }

    // ---- Tail: tiles 20..23, no staging ----
    // T=20 (even parity: cur bA, prefetch bB)
    ds_load_a<1>(AR(0), wave_m, s, quad, aM1);
    ds_load_b2<0>(BR(1), wave_n, s, quad, bB);
    do_mfma<0>(aM0, bA, acc);
    LGKM0;
    BARRIER; SCHEDB;
    ds_load_b2<2>(BR(1), wave_n, s, quad, bB);
    ds_load_a<0>(AR(1), wave_m, s, quad, aM0);
    do_mfma<1>(aM1, bA, acc);
    LGKM0;
    VMC(4);              // forces T22 landed (outstanding was 8: T22,T23)
    BARRIER; SCHEDB;
    // T=21 (odd: cur bB, prefetch bA)
    ds_load_a<1>(AR(1), wave_m, s, quad, aM1);
    ds_load_b2<0>(BR(2), wave_n, s, quad, bA);
    do_mfma<0>(aM0, bB, acc);
    LGKM0;
    BARRIER; SCHEDB;
    ds_load_b2<2>(BR(2), wave_n, s, quad, bA);
    ds_load_a<0>(AR(2), wave_m, s, quad, aM0);
    do_mfma<1>(aM1, bB, acc);
    LGKM0;
    VMC(0);              // all landed; LDS read-only from here
    BARRIER; SCHEDB;
    // T=22, T=23: plain code, compiler-managed waits
    ds_load_a<1>(AR(2), wave_m, s, quad, aM1);
    do_mfma<0>(aM0, bA, acc);
    do_mfma<1>(aM1, bA, acc);
    ds_load_a<0>(AR(3), wave_m, s, quad, aM0);
    ds_load_a<1>(AR(3), wave_m, s, quad, aM1);
    ds_load_b2<0>(BR(3), wave_n, s, quad, bB);
    ds_load_b2<2>(BR(3), wave_n, s, quad, bB);
    do_mfma<0>(aM0, bB, acc);
    do_mfma<1>(aM1, bB, acc);

    #undef AR
    #undef BR

    // ---- Epilogue 1: S_vis corner (C/D layout: col=s, row=quad*4+r) ----
    if (qt < 4 && kt < 4) {
        #pragma unroll
        for (int mi8 = 0; mi8 < 8; ++mi8)
            #pragma unroll
            for (int r = 0; r < 4; ++r) {
                int grow = qt * 256 + wave_m * 128 + mi8 * 16 + quad * 4 + r;
                float* orow = out0 + ((size_t)b * VIS_ + grow) * VIS_ + kt * 256 + wave_n * 64;
                #pragma unroll
                for (int ni = 0; ni < 4; ++ni)
                    orow[ni * 16 + s] = acc[mi8][ni][r];
            }
    }

    // ---- Epilogue 2: fused argmax; alias reduction array onto staging LDS ----
    __syncthreads();
    unsigned long long* red = (unsigned long long*)lds;   // [256 rows][4 wave_n]

    #pragma unroll
    for (int mi8 = 0; mi8 < 8; ++mi8) {
        #pragma unroll
        for (int r = 0; r < 4; ++r) {
            float best = acc[mi8][0][r];
            int bcol = wave_n * 64 + s;
            #pragma unroll
            for (int ni = 1; ni < 4; ++ni) {
                float v = acc[mi8][ni][r];
                if (v > best) { best = v; bcol = wave_n * 64 + ni * 16 + s; }
            }
            int gcol = kt * 256 + bcol;
            unsigned long long key = ((unsigned long long)mapf(best) << 32)
                                   | (unsigned)(HW_ - 1 - gcol);
            #pragma unroll
            for (int m = 1; m < 16; m <<= 1) {
                unsigned long long o = __shfl_xor(key, m, 64);
                if (o > key) key = o;
            }
            if (s == 0)
                red[(wave_m * 128 + mi8 * 16 + quad * 4 + r) * 4 + wave_n] = key;
        }
    }
    __syncthreads();
    if (t < 256) {
        const unsigned long long* rr = red + t * 4;
        unsigned long long k0 = rr[0], k1 = rr[1], k2 = rr[2], k3 = rr[3];
        unsigned long long m01 = k0 > k1 ? k0 : k1;
        unsigned long long m23 = k2 > k3 ? k2 : k3;
        atomicMax(&keys[(size_t)b * HW_ + qt * 256 + t], m01 > m23 ? m01 : m23);
    }
}

// ---------------- fp32 fallback path (round-1, known-good) ----------------
#define BT   64
#define BK   32
#define LDP  68

__global__ __launch_bounds__(256) void gemm_argmax_kernel(
    const float* __restrict__ Q, const float* __restrict__ K,
    float* __restrict__ out0, unsigned long long* __restrict__ ws)
{
    __shared__ float As[BK][LDP];
    __shared__ float Bs[BK][LDP];
    __shared__ unsigned long long red[BT][17];

    const int t  = threadIdx.x;
    const int tx = t & 15;
    const int ty = t >> 4;
    const int k0 = blockIdx.x * BT;
    const int q0 = blockIdx.y * BT;
    const int b  = blockIdx.z;

    const float* Qb = Q + (size_t)b * C_ * HW_;
    const float* Kb = K + (size_t)b * C_ * HW_;

    float acc[4][4] = {{0.f},{0.f},{0.f},{0.f}};

    for (int c0 = 0; c0 < C_; c0 += BK) {
        #pragma unroll
        for (int i = 0; i < 2; ++i) {
            int idx = i * 256 + t;
            int row = idx >> 4;
            int col = (idx & 15) * 4;
            const float4 a  = *(const float4*)(Qb + (size_t)(c0 + row) * HW_ + q0 + col);
            const float4 bv = *(const float4*)(Kb + (size_t)(c0 + row) * HW_ + k0 + col);
            *(float4*)(&As[row][col]) = a;
            *(float4*)(&Bs[row][col]) = bv;
        }
        __syncthreads();
        #pragma unroll
        for (int cc = 0; cc < BK; ++cc) {
            const float4 av = *(const float4*)(&As[cc][ty * 4]);
            const float4 bv = *(const float4*)(&Bs[cc][tx * 4]);
            const float a_[4] = {av.x, av.y, av.z, av.w};
            const float b_[4] = {bv.x, bv.y, bv.z, bv.w};
            #pragma unroll
            for (int i = 0; i < 4; ++i)
                #pragma unroll
                for (int j = 0; j < 4; ++j)
                    acc[i][j] = fmaf(a_[i], b_[j], acc[i][j]);
        }
        __syncthreads();
    }

    if (q0 < VIS_ && k0 < VIS_) {
        #pragma unroll
        for (int i = 0; i < 4; ++i) {
            float4 v = make_float4(acc[i][0], acc[i][1], acc[i][2], acc[i][3]);
            size_t off = (size_t)b * VIS_ * VIS_ + (size_t)(q0 + ty * 4 + i) * VIS_ + (k0 + tx * 4);
            *(float4*)(out0 + off) = v;
        }
    }

    #pragma unroll
    for (int i = 0; i < 4; ++i) {
        float best = acc[i][0];
        int   bj   = 0;
        #pragma unroll
        for (int j = 1; j < 4; ++j)
            if (acc[i][j] > best) { best = acc[i][j]; bj = j; }
        int kidx = k0 + tx * 4 + bj;
        unsigned long long key = ((unsigned long long)mapf(best) << 32)
                               | (unsigned)(HW_ - 1 - kidx);
        red[ty * 4 + i][tx] = key;
    }
    __syncthreads();
    if (t < BT) {
        unsigned long long best = red[t][0];
        #pragma unroll
        for (int j = 1; j < 16; ++j) {
            unsigned long long v = red[t][j];
            if (v > best) best = v;
        }
        atomicMax(&ws[(size_t)b * HW_ + q0 + t], best);
    }
}

extern "C" void kernel_launch(void* const* d_in, const int* in_sizes, int n_in,
                              void* d_out, int out_size, void* d_ws, size_t ws_size,
                              hipStream_t stream) {
    const float* Q = (const float*)d_in[0];
    const float* K = (const float*)d_in[1];
    float* out0 = (float*)d_out;
    float* out1 = out0 + (size_t)B_ * VIS_ * VIS_;

    unsigned long long* keys = (unsigned long long*)d_ws;     // 128 KB
    const size_t keys_bytes = (size_t)B_ * HW_ * 8;
    const size_t exp_elems  = (size_t)B_ * HW_ * KE_;
    const size_t need = keys_bytes + 2 * exp_elems * sizeof(_Float16);

    const int n = B_ * HW_;

    if (ws_size >= need) {
        _Float16* Aexp = (_Float16*)((char*)d_ws + keys_bytes);
        _Float16* Bexp = Aexp + exp_elems;
        split_transpose_kernel<<<dim3(HW_ / 64, C_ / 64, 2 * B_), 256, 0, stream>>>(Q, K, Aexp, Bexp, keys);
        gemm_mfma_kernel<<<dim3((HW_ / 256) * (HW_ / 256) * B_), 512, 0, stream>>>(Aexp, Bexp, out0, keys);
    } else {
        init_ws_kernel<<<(n + 255) / 256, 256, 0, stream>>>(keys, n);
        gemm_argmax_kernel<<<dim3(HW_ / BT, HW_ / BT, B_), 256, 0, stream>>>(Q, K, out0, keys);
    }

    finalize_kernel<<<(n + 255) / 256, 256, 0, stream>>>(keys, out1, n);
}

// Round 7
// 208.085 us; speedup vs baseline: 1.0480x; 1.0480x over previous
//
#include <hip/hip_runtime.h>
#include <stdint.h>

// Problem constants: B=4, C=256, H=W=64 -> HW=4096, vis=1024
#define B_   4
#define C_   256
#define HW_  4096
#define VIS_ 1024
#define KE2  512      // dedup f16 split: [hi(256) | lo(256)] per side

using half8   = __attribute__((ext_vector_type(8))) _Float16;
using floatx4 = __attribute__((ext_vector_type(4))) float;

__device__ __forceinline__ unsigned mapf(float v) {
    unsigned u = __float_as_uint(v);
    return (u & 0x80000000u) ? ~u : (u | 0x80000000u);
}

__global__ void init_ws_kernel(unsigned long long* ws, int n) {
    int i = blockIdx.x * blockDim.x + threadIdx.x;
    if (i < n) ws[i] = 0ull;
}

__global__ void finalize_kernel(const unsigned long long* __restrict__ ws,
                                float* __restrict__ out1, int n) {
    int i = blockIdx.x * blockDim.x + threadIdx.x;
    if (i < n) {
        unsigned kinv = (unsigned)(ws[i] & 0xFFFFFFFFull);
        out1[i] = (float)(HW_ - 1 - (int)kinv);
    }
}

// ---------------- f16-split MFMA path ----------------

// Transpose + split: src[b][c][hw] fp32 -> dst[b][hw][512] f16 = [hi | lo].
// (Dedup vs prior KE=768 [hi,hi,lo]: the hi copy is no longer materialized
// twice; the GEMM reuses hi fragments in registers.) Also zeroes keys.
__global__ __launch_bounds__(256) void split_transpose_kernel(
    const float* __restrict__ Q, const float* __restrict__ K,
    _Float16* __restrict__ Aexp, _Float16* __restrict__ Bexp,
    unsigned long long* __restrict__ keys)
{
    __shared__ float tile[64][65];   // [c][hw], pad 65 to break 8-col bank aliasing
    const int t = threadIdx.x;
    if (blockIdx.y == 0 && blockIdx.z == 0)
        keys[blockIdx.x * 256 + t] = 0ull;   // 64 blocks x 256 thr = 16384 = B_*HW_

    const int hw0 = blockIdx.x * 64;
    const int c0  = blockIdx.y * 64;
    const int z = blockIdx.z, b = z >> 1, which = z & 1;
    const float* src = (which ? K : Q) + (size_t)b * C_ * HW_;
    _Float16* dst = (which ? Bexp : Aexp) + (size_t)b * HW_ * KE2;

    #pragma unroll
    for (int i = 0; i < 4; ++i) {
        int c  = (t >> 4) + i * 16;
        int hw = (t & 15) * 4;
        float4 v = *(const float4*)(src + (size_t)(c0 + c) * HW_ + hw0 + hw);
        tile[c][hw] = v.x; tile[c][hw+1] = v.y; tile[c][hw+2] = v.z; tile[c][hw+3] = v.w;
    }
    __syncthreads();

    #pragma unroll
    for (int i = 0; i < 2; ++i) {
        int id  = t + i * 256;       // 0..511
        int row = id >> 3;           // hw within tile
        int c8  = (id & 7) * 8;      // c offset within 64
        half8 h8, l8;
        #pragma unroll
        for (int j = 0; j < 8; ++j) {
            float v = tile[c8 + j][row];
            _Float16 h = (_Float16)v;
            h8[j] = h;
            l8[j] = (_Float16)(v - (float)h);
        }
        _Float16* base = dst + (size_t)(hw0 + row) * KE2 + c0 + c8;
        *(half8*)(base + 0 * C_) = h8;   // hi segment
        *(half8*)(base + 1 * C_) = l8;   // lo segment
    }
}

__device__ __forceinline__ void gl2lds16(const _Float16* g, _Float16* l) {
    __builtin_amdgcn_global_load_lds(
        (const __attribute__((address_space(1))) void*)g,
        (__attribute__((address_space(3))) void*)l, 16, 0, 0);
}

// ---- 256x256 dedup-split GEMM: 8 chunks of real-k=32, reg-reuse combos ----
//
// Theory (round 7): rounds 2/5/6 all plateaued at ~128-131 us because the
// REQUIRED gl_lds staging rate (32 KB per 1242-cyc MFMA tile = 26.4 B/cyc/CU)
// exceeds the demonstrated sustainable rate (~22 B/cyc, m97). Dedup cuts
// staged bytes 33%: per chunk stage {Ah,Al,Bh,Bl} (64 KB) and compute
// ah*bh + ah*bl + al*bh with hi fragments REUSED in registers (96 MFMA,
// 3725 cyc) -> required rate 17.6 B/cyc. Also 2 barriers per chunk (was 6
// per real-32k); interior is compiler-scheduled (near-optimal per guide).
//
// LDS: 8 regions x 16 KB (region = p*4 + {0:Ah,1:Al,2:Bh,3:Bl}, p = c&1).
// Boundary after chunk c: LGKM0+BARRIER (all reads of buffer p done) ->
// stage chunk c+2 into p (WAR-safe) -> VMC(8) (forces c+1's 8 loads landed;
// outstanding = c+2's 8) -> BARRIER (c+1 visible to all waves).
// Chunk swizzle (involution on 16B chunks within a 64B row):
//   lds chunk (row, ch) holds global chunk ch ^ ((row>>1)&3)

#define BARRIER __builtin_amdgcn_s_barrier()
#define LGKM0   asm volatile("s_waitcnt lgkmcnt(0)" ::: "memory")
#define VMC(n)  asm volatile("s_waitcnt vmcnt(" #n ")" ::: "memory")
#define SCHEDB  __builtin_amdgcn_sched_barrier(0)

// one 256x32 half-panel: 1024 chunks of 16B; 2 global_load_lds per thread.
// LDS dest linear in lane order (gl_lds requirement); global src is
// inverse-swizzled so the read-side XOR sees data in place (rule 21).
__device__ __forceinline__ void stage_half(const _Float16* __restrict__ g,
                                           _Float16* lb, int t, int kbase)
{
    #pragma unroll
    for (int j = 0; j < 2; ++j) {
        const int c   = t + j * 512;
        const int row = c >> 2;
        const int ch  = (c & 3) ^ ((row >> 1) & 3);
        gl2lds16(g + (size_t)row * KE2 + kbase + ch * 8, lb + c * 8);
    }
}

// stage one chunk c into buffer p: Ah,Al,Bh,Bl = 8 gl_lds per thread
__device__ __forceinline__ void stage_chunk(const _Float16* __restrict__ Agl,
                                            const _Float16* __restrict__ Bgl,
                                            _Float16* lds, int p, int c, int t)
{
    stage_half(Agl, lds + (p * 4 + 0) * 8192, t, c * 32);         // Ah
    stage_half(Agl, lds + (p * 4 + 1) * 8192, t, 256 + c * 32);   // Al
    stage_half(Bgl, lds + (p * 4 + 2) * 8192, t, c * 32);         // Bh
    stage_half(Bgl, lds + (p * 4 + 3) * 8192, t, 256 + c * 32);   // Bl
}

template<int MQ>
__device__ __forceinline__ void ds_load_a(const _Float16* base, int wave_m, int s,
                                          int quad, half8 (&a)[4]) {
    #pragma unroll
    for (int mi = 0; mi < 4; ++mi) {
        int row = wave_m * 128 + MQ * 64 + mi * 16 + s;
        int ch  = quad ^ ((row >> 1) & 3);
        a[mi] = *(const half8*)(base + row * 32 + ch * 8);
    }
}

__device__ __forceinline__ void ds_load_b(const _Float16* base, int wave_n, int s,
                                          int quad, half8 (&bfr)[4]) {
    #pragma unroll
    for (int ni = 0; ni < 4; ++ni) {
        int col = wave_n * 64 + ni * 16 + s;
        int ch  = quad ^ ((col >> 1) & 3);
        bfr[ni] = *(const half8*)(base + col * 32 + ch * 8);
    }
}

template<int MQ>
__device__ __forceinline__ void do_mfma(const half8 (&a)[4], const half8 (&bfr)[4],
                                        floatx4 (&acc)[8][4]) {
    __builtin_amdgcn_s_setprio(1);
    #pragma unroll
    for (int mi = 0; mi < 4; ++mi)
        #pragma unroll
        for (int ni = 0; ni < 4; ++ni)
            acc[MQ * 4 + mi][ni] = __builtin_amdgcn_mfma_f32_16x16x32_f16(
                a[mi], bfr[ni], acc[MQ * 4 + mi][ni], 0, 0, 0);
    __builtin_amdgcn_s_setprio(0);
}

// one chunk: 24 ds_read_b128, 96 MFMA per wave; hi-fragments reused.
// All three combos accumulate into the same acc (same summand set as the
// old KE=768 expansion; only fp32 accumulation order differs).
__device__ __forceinline__ void chunk_compute(const _Float16* lds, int p,
    int wave_m, int wave_n, int s, int quad, floatx4 (&acc)[8][4])
{
    const _Float16* Ah = lds + (p * 4 + 0) * 8192;
    const _Float16* Al = lds + (p * 4 + 1) * 8192;
    const _Float16* Bh = lds + (p * 4 + 2) * 8192;
    const _Float16* Bl = lds + (p * 4 + 3) * 8192;
    half8 a0[4], a1[4], bh[4], bl[4];
    ds_load_a<0>(Ah, wave_m, s, quad, a0);
    ds_load_a<1>(Ah, wave_m, s, quad, a1);
    ds_load_b(Bh, wave_n, s, quad, bh);
    do_mfma<0>(a0, bh, acc);          // ah * bh
    do_mfma<1>(a1, bh, acc);
    ds_load_b(Bl, wave_n, s, quad, bl);
    do_mfma<0>(a0, bl, acc);          // ah * bl
    do_mfma<1>(a1, bl, acc);
    ds_load_a<0>(Al, wave_m, s, quad, a0);
    ds_load_a<1>(Al, wave_m, s, quad, a1);
    do_mfma<0>(a0, bh, acc);          // al * bh
    do_mfma<1>(a1, bh, acc);
}

__global__ __launch_bounds__(512, 2) void gemm_mfma_kernel(
    const _Float16* __restrict__ Aexp, const _Float16* __restrict__ Bexp,
    float* __restrict__ out0, unsigned long long* __restrict__ keys)
{
    __shared__ __align__(16) _Float16 lds[65536];   // 128 KiB = 8 regions x 16 KB

    const int t      = threadIdx.x;
    const int lane   = t & 63;
    const int wave   = t >> 6;
    const int quad   = lane >> 4;
    const int s      = lane & 15;
    const int wave_m = wave >> 2;     // 0..1 -> 128 output rows
    const int wave_n = wave & 3;      // 0..3 -> 64 output cols

    // T1: XCD-bijective swizzle (kept; neutral-to-mildly-positive).
    const int n    = blockIdx.x;
    const int wgid = (n & 7) * 128 + (n >> 3);
    const int kt   = wgid & 15;
    const int qt   = (wgid >> 4) & 15;
    const int b    = wgid >> 8;

    const _Float16* Agl = Aexp + (size_t)b * HW_ * KE2 + (size_t)(qt * 256) * KE2;
    const _Float16* Bgl = Bexp + (size_t)b * HW_ * KE2 + (size_t)(kt * 256) * KE2;

    // Prologue: stage chunks 0 (p0) and 1 (p1); VMC(8) forces chunk 0 landed.
    stage_chunk(Agl, Bgl, lds, 0, 0, t);
    stage_chunk(Agl, Bgl, lds, 1, 1, t);
    VMC(8);
    BARRIER; SCHEDB;

    floatx4 acc[8][4] = {};

    // Chunks 0..5: compute c, then boundary {reads-done barrier, stage c+2
    // into c's buffer, VMC(8) -> c+1 landed, barrier}.
    #pragma unroll 1
    for (int c = 0; c < 6; ++c) {
        chunk_compute(lds, c & 1, wave_m, wave_n, s, quad, acc);
        LGKM0;
        BARRIER;
        stage_chunk(Agl, Bgl, lds, c & 1, c + 2, t);
        VMC(8);
        BARRIER; SCHEDB;
    }
    // Chunk 6 (p0); then drain chunk 7's loads (8 outstanding).
    chunk_compute(lds, 0, wave_m, wave_n, s, quad, acc);
    LGKM0;
    BARRIER;
    VMC(0);
    BARRIER; SCHEDB;
    // Chunk 7 (p1); LDS read-only from here.
    chunk_compute(lds, 1, wave_m, wave_n, s, quad, acc);

    // ---- Epilogue 1: S_vis corner (C/D layout: col=s, row=quad*4+r) ----
    if (qt < 4 && kt < 4) {
        #pragma unroll
        for (int mi8 = 0; mi8 < 8; ++mi8)
            #pragma unroll
            for (int r = 0; r < 4; ++r) {
                int grow = qt * 256 + wave_m * 128 + mi8 * 16 + quad * 4 + r;
                float* orow = out0 + ((size_t)b * VIS_ + grow) * VIS_ + kt * 256 + wave_n * 64;
                #pragma unroll
                for (int ni = 0; ni < 4; ++ni)
                    orow[ni * 16 + s] = acc[mi8][ni][r];
            }
    }

    // ---- Epilogue 2: fused argmax; alias reduction array onto staging LDS ----
    __syncthreads();
    unsigned long long* red = (unsigned long long*)lds;   // [256 rows][4 wave_n]

    #pragma unroll
    for (int mi8 = 0; mi8 < 8; ++mi8) {
        #pragma unroll
        for (int r = 0; r < 4; ++r) {
            float best = acc[mi8][0][r];
            int bcol = wave_n * 64 + s;
            #pragma unroll
            for (int ni = 1; ni < 4; ++ni) {
                float v = acc[mi8][ni][r];
                if (v > best) { best = v; bcol = wave_n * 64 + ni * 16 + s; }
            }
            int gcol = kt * 256 + bcol;
            unsigned long long key = ((unsigned long long)mapf(best) << 32)
                                   | (unsigned)(HW_ - 1 - gcol);
            #pragma unroll
            for (int m = 1; m < 16; m <<= 1) {
                unsigned long long o = __shfl_xor(key, m, 64);
                if (o > key) key = o;
            }
            if (s == 0)
                red[(wave_m * 128 + mi8 * 16 + quad * 4 + r) * 4 + wave_n] = key;
        }
    }
    __syncthreads();
    if (t < 256) {
        const unsigned long long* rr = red + t * 4;
        unsigned long long k0 = rr[0], k1 = rr[1], k2 = rr[2], k3 = rr[3];
        unsigned long long m01 = k0 > k1 ? k0 : k1;
        unsigned long long m23 = k2 > k3 ? k2 : k3;
        atomicMax(&keys[(size_t)b * HW_ + qt * 256 + t], m01 > m23 ? m01 : m23);
    }
}

// ---------------- fp32 fallback path (round-1, known-good) ----------------
#define BT   64
#define BK   32
#define LDP  68

__global__ __launch_bounds__(256) void gemm_argmax_kernel(
    const float* __restrict__ Q, const float* __restrict__ K,
    float* __restrict__ out0, unsigned long long* __restrict__ ws)
{
    __shared__ float As[BK][LDP];
    __shared__ float Bs[BK][LDP];
    __shared__ unsigned long long red[BT][17];

    const int t  = threadIdx.x;
    const int tx = t & 15;
    const int ty = t >> 4;
    const int k0 = blockIdx.x * BT;
    const int q0 = blockIdx.y * BT;
    const int b  = blockIdx.z;

    const float* Qb = Q + (size_t)b * C_ * HW_;
    const float* Kb = K + (size_t)b * C_ * HW_;

    float acc[4][4] = {{0.f},{0.f},{0.f},{0.f}};

    for (int c0 = 0; c0 < C_; c0 += BK) {
        #pragma unroll
        for (int i = 0; i < 2; ++i) {
            int idx = i * 256 + t;
            int row = idx >> 4;
            int col = (idx & 15) * 4;
            const float4 a  = *(const float4*)(Qb + (size_t)(c0 + row) * HW_ + q0 + col);
            const float4 bv = *(const float4*)(Kb + (size_t)(c0 + row) * HW_ + k0 + col);
            *(float4*)(&As[row][col]) = a;
            *(float4*)(&Bs[row][col]) = bv;
        }
        __syncthreads();
        #pragma unroll
        for (int cc = 0; cc < BK; ++cc) {
            const float4 av = *(const float4*)(&As[cc][ty * 4]);
            const float4 bv = *(const float4*)(&Bs[cc][tx * 4]);
            const float a_[4] = {av.x, av.y, av.z, av.w};
            const float b_[4] = {bv.x, bv.y, bv.z, bv.w};
            #pragma unroll
            for (int i = 0; i < 4; ++i)
                #pragma unroll
                for (int j = 0; j < 4; ++j)
                    acc[i][j] = fmaf(a_[i], b_[j], acc[i][j]);
        }
        __syncthreads();
    }

    if (q0 < VIS_ && k0 < VIS_) {
        #pragma unroll
        for (int i = 0; i < 4; ++i) {
            float4 v = make_float4(acc[i][0], acc[i][1], acc[i][2], acc[i][3]);
            size_t off = (size_t)b * VIS_ * VIS_ + (size_t)(q0 + ty * 4 + i) * VIS_ + (k0 + tx * 4);
            *(float4*)(out0 + off) = v;
        }
    }

    #pragma unroll
    for (int i = 0; i < 4; ++i) {
        float best = acc[i][0];
        int   bj   = 0;
        #pragma unroll
        for (int j = 1; j < 4; ++j)
            if (acc[i][j] > best) { best = acc[i][j]; bj = j; }
        int kidx = k0 + tx * 4 + bj;
        unsigned long long key = ((unsigned long long)mapf(best) << 32)
                               | (unsigned)(HW_ - 1 - kidx);
        red[ty * 4 + i][tx] = key;
    }
    __syncthreads();
    if (t < BT) {
        unsigned long long best = red[t][0];
        #pragma unroll
        for (int j = 1; j < 16; ++j) {
            unsigned long long v = red[t][j];
            if (v > best) best = v;
        }
        atomicMax(&ws[(size_t)b * HW_ + q0 + t], best);
    }
}

extern "C" void kernel_launch(void* const* d_in, const int* in_sizes, int n_in,
                              void* d_out, int out_size, void* d_ws, size_t ws_size,
                              hipStream_t stream) {
    const float* Q = (const float*)d_in[0];
    const float* K = (const float*)d_in[1];
    float* out0 = (float*)d_out;
    float* out1 = out0 + (size_t)B_ * VIS_ * VIS_;

    unsigned long long* keys = (unsigned long long*)d_ws;     // 128 KB
    const size_t keys_bytes = (size_t)B_ * HW_ * 8;
    const size_t exp_elems  = (size_t)B_ * HW_ * KE2;
    const size_t need = keys_bytes + 2 * exp_elems * sizeof(_Float16);

    const int n = B_ * HW_;

    if (ws_size >= need) {
        _Float16* Aexp = (_Float16*)((char*)d_ws + keys_bytes);
        _Float16* Bexp = Aexp + exp_elems;
        split_transpose_kernel<<<dim3(HW_ / 64, C_ / 64, 2 * B_), 256, 0, stream>>>(Q, K, Aexp, Bexp, keys);
        gemm_mfma_kernel<<<dim3((HW_ / 256) * (HW_ / 256) * B_), 512, 0, stream>>>(Aexp, Bexp, out0, keys);
    } else {
        init_ws_kernel<<<(n + 255) / 256, 256, 0, stream>>>(keys, n);
        gemm_argmax_kernel<<<dim3(HW_ / BT, HW_ / BT, B_), 256, 0, stream>>>(Q, K, out0, keys);
    }

    finalize_kernel<<<(n + 255) / 256, 256, 0, stream>>>(keys, out1, n);
}